// Round 8
// baseline (611.936 us; speedup 1.0000x reference)
//
#include <hip/hip_runtime.h>
#include <hip/hip_bf16.h>

#define N_NODES   50000
#define N_REL     16
#define HID       128
#define N_EDGES   1600000
#define N_TILES   3125          // N_NODES/16
#define N_BINS    800000        // fine bins (tile, rel, m)
#define N_RUNS    50000         // (tile, rel) runs of 16 fine bins
#define N_SCANBLK 49            // ceil(N_RUNS/1024)
#define N_MBLK    1563          // ceil(3125/2): M=32 per block
#define PAYLOAD_CAP 2400064     // E + 50000*15 pad worst case + slack
#define BS_LAYER  278528        // (16 rel + root)*4kk*8cb frags * 512 ushorts
#define AG_STRIDE 136           // ushorts per agg row (272 B, 16-B aligned)

typedef unsigned short ushort_t;
typedef __attribute__((ext_vector_type(8))) short short8;
typedef __attribute__((ext_vector_type(4))) float f32x4;

union BF2U { __hip_bfloat162 h; unsigned u; };

__device__ __forceinline__ unsigned pack_bf16_2(float x, float y) {
  BF2U c; c.h = __float22bfloat162_rn(make_float2(x, y));
  return c.u;
}

// barrier WITHOUT vmcnt drain (LDS ops drained; global prefetches keep flying)
__device__ __forceinline__ void lds_barrier() {
  asm volatile("s_waitcnt lgkmcnt(0)\n\ts_barrier" ::: "memory");
}

// ---------------- setup kernels ----------------

__global__ __launch_bounds__(256) void k_hist(const int* __restrict__ ei,
                                              const int* __restrict__ et,
                                              int* __restrict__ cnt,
                                              int* __restrict__ rank) {
  int e = blockIdx.x * 256 + threadIdx.x;   // grid covers E exactly
  int tgt = ei[N_EDGES + e];
  int r   = et[e];
  int key = ((tgt >> 4) << 8) | (r << 4) | (tgt & 15);
  rank[e] = atomicAdd(&cnt[key], 1);        // rank within bin falls out free
}

// FUSED: per-run padded total (-> run_start, pre-scan) + per-1024-block sum
__global__ __launch_bounds__(1024) void k_runpad_btot(const int* __restrict__ cnt,
                                                      int* __restrict__ run_start,
                                                      int* __restrict__ totals) {
  __shared__ int s[1024];
  int t = threadIdx.x, blk = blockIdx.x;
  int r = blk * 1024 + t;
  int v = 0;
  if (r < N_RUNS) {
    const int4* c4 = (const int4*)(cnt + r * 16);
    int sum = 0;
#pragma unroll
    for (int j = 0; j < 4; ++j) { int4 w = c4[j]; sum += w.x + w.y + w.z + w.w; }
    v = (sum + 15) & ~15;
    run_start[r] = v;                       // padded totals (pre-scan)
  }
  s[t] = v; __syncthreads();
  for (int ofs = 512; ofs > 0; ofs >>= 1) {
    if (t < ofs) s[t] += s[t + ofs];
    __syncthreads();
  }
  if (t == 0) totals[blk] = s[0];
}

__global__ __launch_bounds__(1024) void k_scan_totals(int* totals, int* endp, int nblk) {
  __shared__ int s[1024];
  int t = threadIdx.x;
  int v = (t < nblk) ? totals[t] : 0;
  s[t] = v; __syncthreads();
  for (int ofs = 1; ofs < 1024; ofs <<= 1) {
    int x = (t >= ofs) ? s[t - ofs] : 0;
    __syncthreads();
    s[t] += x;
    __syncthreads();
  }
  if (t < nblk) totals[t] = s[t] - v;      // exclusive block offsets
  if (t == nblk - 1) *endp = s[t];         // grand total (padded edge count)
}

// FUSED: within-block scan of padded totals -> run_start, then fine-bin
// start offsets + dummy-fill of the pad region (one pass, no extra launch)
__global__ __launch_bounds__(1024) void k_scan_fineoff(int* __restrict__ run_start,
                                                       const int* __restrict__ totals,
                                                       const int* __restrict__ cnt,
                                                       int* __restrict__ fine_start,
                                                       unsigned* __restrict__ payload) {
  __shared__ int s[1024];
  int t = threadIdx.x, blk = blockIdx.x;
  int r = blk * 1024 + t;
  int v = (r < N_RUNS) ? run_start[r] : 0;  // padded total of my run
  s[t] = v; __syncthreads();
  for (int ofs = 1; ofs < 1024; ofs <<= 1) {
    int x = (t >= ofs) ? s[t - ofs] : 0;
    __syncthreads();
    s[t] += x;
    __syncthreads();
  }
  if (r < N_RUNS) {
    int base = totals[blk] + s[t] - v;      // exclusive global padded offset
    run_start[r] = base;
    int pfx = 0;
#pragma unroll 4
    for (int i = 0; i < 16; ++i) {
      fine_start[r * 16 + i] = base + pfx;
      pfx += cnt[r * 16 + i];
    }
    const unsigned dummy = ((unsigned)N_NODES << 16) | (1u << 4) | 15u;
    for (int j = base + pfx; j < base + v; ++j) payload[j] = dummy;
  }
}

// payload = src:31..16 | bin_cnt:15..4 | m:3..0 — atomic-free placement
__global__ __launch_bounds__(256) void k_sort(const int* __restrict__ ei,
                                              const int* __restrict__ et,
                                              const int* __restrict__ cnt,
                                              const int* __restrict__ fine_start,
                                              const int* __restrict__ rank,
                                              unsigned* __restrict__ payload) {
  int e = blockIdx.x * 256 + threadIdx.x;
  int src = ei[e];
  int tgt = ei[N_EDGES + e];
  int r   = et[e];
  int key = ((tgt >> 4) << 8) | (r << 4) | (tgt & 15);
  int c = cnt[key]; c = c > 4095 ? 4095 : c;
  int pos = fine_start[key] + rank[e];
  payload[pos] = ((unsigned)src << 16) | ((unsigned)c << 4) | (unsigned)(tgt & 15);
}

// Bs fragment-ordered: frag = ((r*4+kk)*8+cb), r 0..16 (16=root); within frag
// 64 lanes x 8 bf16: lane -> col cb*16+(lane&15), k = kk*32+(lane>>4)*8+j.
__global__ __launch_bounds__(256) void k_bt(const float* __restrict__ W,
                                            const float* __restrict__ root,
                                            ushort_t* __restrict__ Bs) {
  int idx = blockIdx.x * 256 + threadIdx.x;    // 3*544*64 = 104448 exact
  int lane = idx & 63;
  int fl   = idx >> 6;                          // l*544 + frag
  int frag = fl % 544;
  int l    = fl / 544;
  int cb = frag & 7, kk = (frag >> 3) & 3, r = frag >> 5;
  int col = cb * 16 + (lane & 15);
  int d0  = kk * 32 + (lane >> 4) * 8;
  const float* srcp = (r < 16)
      ? W + ((size_t)(l * N_REL + r) * HID + d0) * HID + col
      : root + ((size_t)l * HID + d0) * HID + col;
  ushort_t out[8];
#pragma unroll
  for (int j = 0; j < 8; ++j) {
    union { __hip_bfloat16 h; ushort_t u; } c;
    c.h = __float2bfloat16(srcp[(size_t)j * HID]);
    out[j] = c.u;
  }
  *(short8*)(Bs + ((size_t)fl << 9) + lane * 8) = *(short8*)out;
}

// xh_a = bf16(x); also zero the dummy rows (row N_NODES) of both buffers
__global__ __launch_bounds__(256) void k_xh(const float* __restrict__ xin,
                                            ushort_t* __restrict__ xh_a,
                                            ushort_t* __restrict__ xh_b) {
  int i = blockIdx.x * 256 + threadIdx.x;      // grid = N*H/4 exact
  float4 v = ((const float4*)xin)[i];
  uint2 u;
  u.x = pack_bf16_2(v.x, v.y);
  u.y = pack_bf16_2(v.z, v.w);
  ((uint2*)xh_a)[i] = u;
  if (blockIdx.x == 0 && threadIdx.x < 64) {
    uint2 z = {0u, 0u};
    ushort_t* dst = (threadIdx.x < 32) ? xh_a : xh_b;
    int k = threadIdx.x & 31;
    *(uint2*)(dst + (size_t)N_NODES * HID + k * 4) = z;
  }
}

// ---------------- fused per-layer kernel: producer/consumer waves ----------
// Block = 32 nodes (2 tiles), 4 waves. Waves 0,1 = PRODUCERS (rel 2s+p at
// step s), register-RLE into double-buffered LDS agg. Waves 2,3 = CONSUMERS
// (B frags + MFMA). sched_barrier(0) after each issue group pins prefetched
// gathers HIGH (round-7 VGPR=60 proved the compiler was sinking them to
// their use, destroying the pipeline); lds_barrier keeps them flying across
// the step barrier. launch_bounds (256,3) gives the ~140-VGPR headroom the
// live prefetch window needs without spilling.

__global__ __launch_bounds__(256, 3) void k_main(const ushort_t* __restrict__ xh,
                                                 ushort_t* __restrict__ xh_out,
                                                 float* __restrict__ fout,
                                                 const ushort_t* __restrict__ Bs,
                                                 const float* __restrict__ bias,
                                                 const int* __restrict__ run_start,
                                                 const unsigned* __restrict__ payload,
                                                 int write_f32) {
  __shared__ alignas(16) ushort_t agg[2][2][32][AG_STRIDE];   // 34.8 KB

  const int tile0 = blockIdx.x * 2;
  const int tid   = threadIdx.x;
  const int wave  = tid >> 6;
  const int lane  = tid & 63;
  const int m16   = lane & 15;
  const int q     = lane >> 4;
  const unsigned* xh32 = (const unsigned*)xh;

  if (wave < 2) {
    // ======================= PRODUCER =======================
    const int p = wave;
    // run bounds, 32 values lane-parallel: lane = s*4 + t*2 + h
    int ebv = 0;
    {
      int s8 = lane >> 2, t2 = (lane >> 1) & 1, h = lane & 1;
      int tt = tile0 + t2;
      int idx = (tt < N_TILES) ? (tt * 16 + s8 * 2 + p + h) : N_RUNS;
      if (lane < 32) ebv = run_start[idx];
    }

#define ISSUE16(DST, PV, JB)                                                  \
    _Pragma("unroll")                                                         \
    for (int k1 = 0; k1 < 16; ++k1) {                                         \
      unsigned spq = (unsigned)__builtin_amdgcn_readlane(PV, (JB) + k1);      \
      DST[k1] = xh32[(spq >> 16) * 64 + lane];                                \
    }

#define FLUSHM(TB, BUF)                                                       \
    if (mcur >= 0) {                                                          \
      float sc = __builtin_amdgcn_rcpf((float)scnt);                          \
      *(unsigned*)&agg[BUF][p][(TB) + mcur][lane * 2] =                       \
          pack_bf16_2(a0 * sc, a1 * sc);                                      \
    }

#define CONSUME1(SPK, XV, TB, BUF)                                            \
    {                                                                         \
      int mk = (int)((SPK) & 15u);                                            \
      if (mk != mcur) {                                                       \
        FLUSHM(TB, BUF);                                                      \
        mcur = mk; scnt = (int)(((SPK) >> 4) & 4095u);                        \
        a0 = 0.f; a1 = 0.f;                                                   \
      }                                                                       \
      a0 += __uint_as_float((XV) << 16);                                      \
      a1 += __uint_as_float((XV) & 0xffff0000u);                              \
    }

#define CONS16(PV, JB, SLOT, TB, BUF)                                         \
    _Pragma("unroll")                                                         \
    for (int k2 = 0; k2 < 16; ++k2) {                                         \
      unsigned spk = (unsigned)__builtin_amdgcn_readlane(PV, (JB) + k2);      \
      CONSUME1(spk, SLOT[k2], TB, BUF);                                       \
    }

// run consume: b0,b1 prefetched in B0,B1; b2 prefetched in xqE; b3 + >64 rare
#define RUNX(PV, E0, E1, CNT, B0, B1, TB)                                     \
    {                                                                         \
      int mcur = -1, scnt = 1;                                                \
      float a0 = 0.f, a1 = 0.f;                                               \
      if ((CNT) > 0) {                                                        \
        CONS16(PV, 0, B0, TB, buf);                                           \
        if ((CNT) > 16) {                                                     \
          CONS16(PV, 16, B1, TB, buf);                                        \
          if ((CNT) > 32) {                                                   \
            CONS16(PV, 32, xqE, TB, buf);                                     \
            if ((CNT) > 48) {                                                 \
              ISSUE16(xqE, PV, 48);                                           \
              CONS16(PV, 48, xqE, TB, buf);                                   \
            }                                                                 \
          }                                                                   \
        }                                                                     \
        for (int c0 = (E0) + 64; c0 < (E1); c0 += 16) { /* very rare */       \
          int pvx = (int)payload[c0 + lane];                                  \
          ISSUE16(xqE, pvx, 0);                                               \
          CONS16(pvx, 0, xqE, TB, buf);                                       \
        }                                                                     \
        FLUSHM(TB, buf);                                                      \
      }                                                                       \
    }

    unsigned xqA[16], xqB[16], xqC[16], xqD[16], xqE[16];

    // step-0 bounds + payloads + across-barrier prefetch of both b0's
    int e00 = __builtin_amdgcn_readlane(ebv, 0);
    int e01 = __builtin_amdgcn_readlane(ebv, 1);
    int e10 = __builtin_amdgcn_readlane(ebv, 2);
    int e11 = __builtin_amdgcn_readlane(ebv, 3);
    int pv0 = (int)payload[e00 + lane];
    int pv1 = (int)payload[e10 + lane];
    ISSUE16(xqA, pv0, 0);
    ISSUE16(xqC, pv1, 0);
    __builtin_amdgcn_sched_barrier(0);        // pin prologue prefetches high

    for (int s = 0; s < 8; ++s) {
      const int buf = s & 1;
      int cnt0 = e01 - e00, cnt1 = e11 - e10;

      // early in-step issues: b1 of both runs, b2 of run0
      if (cnt0 > 16) ISSUE16(xqB, pv0, 16);
      if (cnt1 > 16) ISSUE16(xqD, pv1, 16);
      if (cnt0 > 32) ISSUE16(xqE, pv0, 32);

      // next step's payload chunks early (latency hidden under consume)
      int f00 = e00, f01 = e01, f10 = e10, f11 = e11;
      int pvn0 = pv0, pvn1 = pv1;
      if (s < 7) {
        f00 = __builtin_amdgcn_readlane(ebv, (s + 1) * 4 + 0);
        f01 = __builtin_amdgcn_readlane(ebv, (s + 1) * 4 + 1);
        f10 = __builtin_amdgcn_readlane(ebv, (s + 1) * 4 + 2);
        f11 = __builtin_amdgcn_readlane(ebv, (s + 1) * 4 + 3);
        pvn0 = (int)payload[f00 + lane];
        pvn1 = (int)payload[f10 + lane];
      }
      __builtin_amdgcn_sched_barrier(0);      // loads above may not sink

      // zero my slice (32 rows x 128 dims): 8 ds_write_b128/lane
      {
        short8 z = {0, 0, 0, 0, 0, 0, 0, 0};
#pragma unroll
        for (int i = 0; i < 8; ++i)
          *(short8*)&agg[buf][p][i * 4 + q][m16 * 8] = z;
      }

      RUNX(pv0, e00, e01, cnt0, xqA, xqB, 0);
      if (cnt1 > 32) ISSUE16(xqE, pv1, 32);   // r1.b2 flies under r1.b0/b1
      __builtin_amdgcn_sched_barrier(0);
      RUNX(pv1, e10, e11, cnt1, xqC, xqD, 16);

      if (s < 7) {                            // across-barrier prefetch b0's
        e00 = f00; e01 = f01; e10 = f10; e11 = f11;
        pv0 = pvn0; pv1 = pvn1;
        ISSUE16(xqA, pv0, 0);
        ISSUE16(xqC, pv1, 0);
      }
      __builtin_amdgcn_sched_barrier(0);      // keep prefetches above barrier
      lds_barrier();                          // NO vmcnt drain
    }
#undef RUNX
#undef CONS16
#undef CONSUME1
#undef FLUSHM
#undef ISSUE16
    return;                                   // producers exit; 8 barriers done
  }

  // ======================= CONSUMER =======================
  const int c = wave - 2;                 // owns cols c*64 .. c*64+64
  f32x4 acc[2][4];
#pragma unroll
  for (int t = 0; t < 2; ++t)
#pragma unroll
    for (int i = 0; i < 4; ++i) acc[t][i] = (f32x4){0.f, 0.f, 0.f, 0.f};

  for (int s = 0; s < 8; ++s) {
    lds_barrier();                        // barrier s: agg[s&1] ready
#pragma unroll
    for (int rp = 0; rp < 2; ++rp) {
      int rel = s * 2 + rp;
      short8 Bf[4][4];
#pragma unroll
      for (int kk = 0; kk < 4; ++kk)
#pragma unroll
        for (int i = 0; i < 4; ++i)
          Bf[kk][i] = *(const short8*)(Bs +
              ((size_t)((rel * 4 + kk) * 8 + (c * 4 + i)) << 9) + lane * 8);
#pragma unroll
      for (int kk = 0; kk < 4; ++kk) {
        short8 A0 = *(const short8*)&agg[s & 1][rp][m16][kk * 32 + q * 8];
        short8 A1 = *(const short8*)&agg[s & 1][rp][16 + m16][kk * 32 + q * 8];
#pragma unroll
        for (int i = 0; i < 4; ++i) {
          acc[0][i] = __builtin_amdgcn_mfma_f32_16x16x32_bf16(A0, Bf[kk][i], acc[0][i], 0, 0, 0);
          acc[1][i] = __builtin_amdgcn_mfma_f32_16x16x32_bf16(A1, Bf[kk][i], acc[1][i], 0, 0, 0);
        }
      }
    }
  }

  // ---- root (rel index 16): A from global xh rows of this block ----
  {
    short8 Bf[4][4];
#pragma unroll
    for (int kk = 0; kk < 4; ++kk)
#pragma unroll
      for (int i = 0; i < 4; ++i)
        Bf[kk][i] = *(const short8*)(Bs +
            ((size_t)((16 * 4 + kk) * 8 + (c * 4 + i)) << 9) + lane * 8);
    int r0 = tile0 * 16 + m16;      if (r0 > N_NODES) r0 = N_NODES;
    int r1 = tile0 * 16 + 16 + m16; if (r1 > N_NODES) r1 = N_NODES;
#pragma unroll
    for (int kk = 0; kk < 4; ++kk) {
      short8 A0 = *(const short8*)(xh + (size_t)r0 * HID + kk * 32 + q * 8);
      short8 A1 = *(const short8*)(xh + (size_t)r1 * HID + kk * 32 + q * 8);
#pragma unroll
      for (int i = 0; i < 4; ++i) {
        acc[0][i] = __builtin_amdgcn_mfma_f32_16x16x32_bf16(A0, Bf[kk][i], acc[0][i], 0, 0, 0);
        acc[1][i] = __builtin_amdgcn_mfma_f32_16x16x32_bf16(A1, Bf[kk][i], acc[1][i], 0, 0, 0);
      }
    }
  }

  // ---- epilogue: bias (+relu+bf16 or f32). C/D: col=lane&15, row=q*4+reg
  float bvv[4];
#pragma unroll
  for (int i = 0; i < 4; ++i) bvv[i] = bias[(c * 4 + i) * 16 + m16];
  int rbase = tile0 * 16 + q * 4;
#pragma unroll
  for (int t = 0; t < 2; ++t)
#pragma unroll
    for (int rg = 0; rg < 4; ++rg) {
      int row = rbase + t * 16 + rg;
      if (row < N_NODES) {
#pragma unroll
        for (int i = 0; i < 4; ++i) {
          float v = acc[t][i][rg] + bvv[i];
          int col = (c * 4 + i) * 16 + m16;
          if (write_f32) {
            fout[(size_t)row * HID + col] = v;
          } else {
            v = fmaxf(v, 0.f);
            union { __hip_bfloat16 h; ushort_t u; } cv;
            cv.h = __float2bfloat16(v);
            xh_out[(size_t)row * HID + col] = cv.u;
          }
        }
      }
    }
}

// ---------------- host ----------------

extern "C" void kernel_launch(void* const* d_in, const int* in_sizes, int n_in,
                              void* d_out, int out_size, void* d_ws, size_t ws_size,
                              hipStream_t stream) {
  const int*   ei        = (const int*)d_in[0];     // (2, E) int32
  const int*   et        = (const int*)d_in[1];     // (E,)   int32
  const float* node_init = (const float*)d_in[2];   // (N, H) f32
  const float* W         = (const float*)d_in[3];   // (3, 16, H, H) f32
  const float* root      = (const float*)d_in[4];   // (3, H, H) f32
  const float* bias      = (const float*)d_in[5];   // (3, H) f32
  float* outp = (float*)d_out;

  char* ws = (char*)d_ws;
  size_t o = 0;
  auto carve = [&](size_t bytes) { char* p = ws + o; o = (o + bytes + 255) & ~(size_t)255; return p; };
  ushort_t* xh_a       = (ushort_t*)carve((size_t)(N_NODES + 1) * HID * 2);   // +dummy row
  ushort_t* xh_b       = (ushort_t*)carve((size_t)(N_NODES + 1) * HID * 2);
  unsigned* payload    = (unsigned*)carve((size_t)PAYLOAD_CAP * 4);
  int*      cnt        = (int*)     carve((size_t)N_BINS * 4);
  int*      fine_start = (int*)     carve((size_t)N_BINS * 4);
  int*      rank       = (int*)     carve((size_t)N_EDGES * 4);
  int*      run_start  = (int*)     carve((size_t)(N_RUNS + 1) * 4);
  int*      totals     = (int*)     carve((size_t)N_SCANBLK * 4);
  ushort_t* Bs         = (ushort_t*)carve((size_t)3 * BS_LAYER * 2);
  (void)ws_size; (void)n_in; (void)in_sizes; (void)out_size;

  // ---- setup: padded counting sort by (tile, rel, m) + B swizzle (8 launches)
  hipMemsetAsync(cnt, 0, (size_t)N_BINS * 4, stream);
  hipLaunchKernelGGL(k_hist,         dim3(N_EDGES / 256), dim3(256), 0, stream, ei, et, cnt, rank);
  hipLaunchKernelGGL(k_runpad_btot,  dim3(N_SCANBLK), dim3(1024), 0, stream, cnt, run_start, totals);
  hipLaunchKernelGGL(k_scan_totals,  dim3(1), dim3(1024), 0, stream, totals, run_start + N_RUNS, N_SCANBLK);
  hipLaunchKernelGGL(k_scan_fineoff, dim3(N_SCANBLK), dim3(1024), 0, stream, run_start, totals, cnt, fine_start, payload);
  hipLaunchKernelGGL(k_sort,         dim3(N_EDGES / 256), dim3(256), 0, stream, ei, et, cnt, fine_start, rank, payload);
  hipLaunchKernelGGL(k_bt,           dim3(3 * 544 * 64 / 256), dim3(256), 0, stream, W, root, Bs);
  hipLaunchKernelGGL(k_xh,           dim3(N_NODES * HID / 4 / 256), dim3(256), 0, stream, node_init, xh_a, xh_b);

  // ---- 3 layers, bf16 ping-pong; relu fused into epilogue of layers 0,1 ----
  hipLaunchKernelGGL(k_main, dim3(N_MBLK), dim3(256), 0, stream,
                     xh_a, xh_b, (float*)nullptr,
                     Bs + (size_t)0 * BS_LAYER, bias + 0 * HID, run_start, payload, 0);
  hipLaunchKernelGGL(k_main, dim3(N_MBLK), dim3(256), 0, stream,
                     xh_b, xh_a, (float*)nullptr,
                     Bs + (size_t)1 * BS_LAYER, bias + 1 * HID, run_start, payload, 0);
  hipLaunchKernelGGL(k_main, dim3(N_MBLK), dim3(256), 0, stream,
                     xh_a, (ushort_t*)nullptr, outp,
                     Bs + (size_t)2 * BS_LAYER, bias + 2 * HID, run_start, payload, 1);
}

// Round 9
// 509.021 us; speedup vs baseline: 1.2022x; 1.2022x over previous
//
#include <hip/hip_runtime.h>
#include <hip/hip_bf16.h>

#define N_NODES   50000
#define N_REL     16
#define HID       128
#define N_EDGES   1600000
#define N_TILES   3125          // N_NODES/16
#define N_BINS    800000        // fine bins (tile, rel, m)
#define N_RUNS    50000         // (tile, rel) runs of 16 fine bins
#define N_SCANBLK 49            // ceil(N_RUNS/1024)
#define N_MBLK    1563          // ceil(3125/2): M=32 per block
#define PAYLOAD_CAP 2400064     // E + 50000*15 pad worst case + slack
#define BS_LAYER  278528        // (16 rel + root)*4kk*8cb frags * 512 ushorts
#define AG_STRIDE 136           // ushorts per agg row (272 B, 16-B aligned)

typedef unsigned short ushort_t;
typedef __attribute__((ext_vector_type(8))) short short8;
typedef __attribute__((ext_vector_type(4))) float f32x4;

union BF2U { __hip_bfloat162 h; unsigned u; };

__device__ __forceinline__ unsigned pack_bf16_2(float x, float y) {
  BF2U c; c.h = __float22bfloat162_rn(make_float2(x, y));
  return c.u;
}

// barrier WITHOUT vmcnt drain (LDS ops drained; global prefetches keep flying)
__device__ __forceinline__ void lds_barrier() {
  asm volatile("s_waitcnt lgkmcnt(0)\n\ts_barrier" ::: "memory");
}

// ---------------- setup kernels ----------------

__global__ __launch_bounds__(256) void k_hist(const int* __restrict__ ei,
                                              const int* __restrict__ et,
                                              int* __restrict__ cnt,
                                              int* __restrict__ rank) {
  int e = blockIdx.x * 256 + threadIdx.x;   // grid covers E exactly
  int tgt = ei[N_EDGES + e];
  int r   = et[e];
  int key = ((tgt >> 4) << 8) | (r << 4) | (tgt & 15);
  rank[e] = atomicAdd(&cnt[key], 1);        // rank within bin falls out free
}

// FUSED: per-run padded total (-> run_start, pre-scan) + per-1024-block sum
__global__ __launch_bounds__(1024) void k_runpad_btot(const int* __restrict__ cnt,
                                                      int* __restrict__ run_start,
                                                      int* __restrict__ totals) {
  __shared__ int s[1024];
  int t = threadIdx.x, blk = blockIdx.x;
  int r = blk * 1024 + t;
  int v = 0;
  if (r < N_RUNS) {
    const int4* c4 = (const int4*)(cnt + r * 16);
    int sum = 0;
#pragma unroll
    for (int j = 0; j < 4; ++j) { int4 w = c4[j]; sum += w.x + w.y + w.z + w.w; }
    v = (sum + 15) & ~15;
    run_start[r] = v;                       // padded totals (pre-scan)
  }
  s[t] = v; __syncthreads();
  for (int ofs = 512; ofs > 0; ofs >>= 1) {
    if (t < ofs) s[t] += s[t + ofs];
    __syncthreads();
  }
  if (t == 0) totals[blk] = s[0];
}

__global__ __launch_bounds__(1024) void k_scan_totals(int* totals, int* endp, int nblk) {
  __shared__ int s[1024];
  int t = threadIdx.x;
  int v = (t < nblk) ? totals[t] : 0;
  s[t] = v; __syncthreads();
  for (int ofs = 1; ofs < 1024; ofs <<= 1) {
    int x = (t >= ofs) ? s[t - ofs] : 0;
    __syncthreads();
    s[t] += x;
    __syncthreads();
  }
  if (t < nblk) totals[t] = s[t] - v;      // exclusive block offsets
  if (t == nblk - 1) *endp = s[t];         // grand total (padded edge count)
}

// FUSED: within-block scan of padded totals -> run_start, then fine-bin
// start offsets + dummy-fill of the pad region (one pass, no extra launch)
__global__ __launch_bounds__(1024) void k_scan_fineoff(int* __restrict__ run_start,
                                                       const int* __restrict__ totals,
                                                       const int* __restrict__ cnt,
                                                       int* __restrict__ fine_start,
                                                       unsigned* __restrict__ payload) {
  __shared__ int s[1024];
  int t = threadIdx.x, blk = blockIdx.x;
  int r = blk * 1024 + t;
  int v = (r < N_RUNS) ? run_start[r] : 0;  // padded total of my run
  s[t] = v; __syncthreads();
  for (int ofs = 1; ofs < 1024; ofs <<= 1) {
    int x = (t >= ofs) ? s[t - ofs] : 0;
    __syncthreads();
    s[t] += x;
    __syncthreads();
  }
  if (r < N_RUNS) {
    int base = totals[blk] + s[t] - v;      // exclusive global padded offset
    run_start[r] = base;
    int pfx = 0;
#pragma unroll 4
    for (int i = 0; i < 16; ++i) {
      fine_start[r * 16 + i] = base + pfx;
      pfx += cnt[r * 16 + i];
    }
    const unsigned dummy = ((unsigned)N_NODES << 16) | (1u << 4) | 15u;
    for (int j = base + pfx; j < base + v; ++j) payload[j] = dummy;
  }
}

// payload = src:31..16 | bin_cnt:15..4 | m:3..0 — atomic-free placement
__global__ __launch_bounds__(256) void k_sort(const int* __restrict__ ei,
                                              const int* __restrict__ et,
                                              const int* __restrict__ cnt,
                                              const int* __restrict__ fine_start,
                                              const int* __restrict__ rank,
                                              unsigned* __restrict__ payload) {
  int e = blockIdx.x * 256 + threadIdx.x;
  int src = ei[e];
  int tgt = ei[N_EDGES + e];
  int r   = et[e];
  int key = ((tgt >> 4) << 8) | (r << 4) | (tgt & 15);
  int c = cnt[key]; c = c > 4095 ? 4095 : c;
  int pos = fine_start[key] + rank[e];
  payload[pos] = ((unsigned)src << 16) | ((unsigned)c << 4) | (unsigned)(tgt & 15);
}

// Bs fragment-ordered: frag = ((r*4+kk)*8+cb), r 0..16 (16=root); within frag
// 64 lanes x 8 bf16: lane -> col cb*16+(lane&15), k = kk*32+(lane>>4)*8+j.
__global__ __launch_bounds__(256) void k_bt(const float* __restrict__ W,
                                            const float* __restrict__ root,
                                            ushort_t* __restrict__ Bs) {
  int idx = blockIdx.x * 256 + threadIdx.x;    // 3*544*64 = 104448 exact
  int lane = idx & 63;
  int fl   = idx >> 6;                          // l*544 + frag
  int frag = fl % 544;
  int l    = fl / 544;
  int cb = frag & 7, kk = (frag >> 3) & 3, r = frag >> 5;
  int col = cb * 16 + (lane & 15);
  int d0  = kk * 32 + (lane >> 4) * 8;
  const float* srcp = (r < 16)
      ? W + ((size_t)(l * N_REL + r) * HID + d0) * HID + col
      : root + ((size_t)l * HID + d0) * HID + col;
  ushort_t out[8];
#pragma unroll
  for (int j = 0; j < 8; ++j) {
    union { __hip_bfloat16 h; ushort_t u; } c;
    c.h = __float2bfloat16(srcp[(size_t)j * HID]);
    out[j] = c.u;
  }
  *(short8*)(Bs + ((size_t)fl << 9) + lane * 8) = *(short8*)out;
}

// xh_a = bf16(x); also zero the dummy rows (row N_NODES) of both buffers
__global__ __launch_bounds__(256) void k_xh(const float* __restrict__ xin,
                                            ushort_t* __restrict__ xh_a,
                                            ushort_t* __restrict__ xh_b) {
  int i = blockIdx.x * 256 + threadIdx.x;      // grid = N*H/4 exact
  float4 v = ((const float4*)xin)[i];
  uint2 u;
  u.x = pack_bf16_2(v.x, v.y);
  u.y = pack_bf16_2(v.z, v.w);
  ((uint2*)xh_a)[i] = u;
  if (blockIdx.x == 0 && threadIdx.x < 64) {
    uint2 z = {0u, 0u};
    ushort_t* dst = (threadIdx.x < 32) ? xh_a : xh_b;
    int k = threadIdx.x & 31;
    *(uint2*)(dst + (size_t)N_NODES * HID + k * 4) = z;
  }
}

// ---------------- fused per-layer kernel: 4 producer + 4 consumer waves ----
// Block = 512 threads = 8 waves, 32 nodes (2 tiles). Round-8 lesson: the
// compiler always sinks gather loads to their use (VGPR=60 across r6-r8),
// so per-wave prefetch depth is unfixable at source level. This round gets
// memory-level parallelism from WAVE COUNT instead: 4 producer waves/block
// (split by tile x rel-parity; each handles one ~32-edge padded run per
// step) x 4 blocks/CU = 16 producer waves/CU (~3.5x round 8). 4 consumer
// waves each own 32 output cols (Bf[4][2]=32 VGPR -> fits 64-VGPR cap of
// 8 waves/SIMD). Runs padded to x16 -> all batches full, no tail guards.

__global__ __launch_bounds__(512, 8) void k_main(const ushort_t* __restrict__ xh,
                                                 ushort_t* __restrict__ xh_out,
                                                 float* __restrict__ fout,
                                                 const ushort_t* __restrict__ Bs,
                                                 const float* __restrict__ bias,
                                                 const int* __restrict__ run_start,
                                                 const unsigned* __restrict__ payload,
                                                 int write_f32) {
  __shared__ alignas(16) ushort_t agg[2][2][32][AG_STRIDE];   // 34.8 KB

  const int tile0 = blockIdx.x * 2;
  const int tid   = threadIdx.x;
  const int wave  = tid >> 6;
  const int lane  = tid & 63;
  const int m16   = lane & 15;
  const int q     = lane >> 4;
  const unsigned* xh32 = (const unsigned*)xh;

  if (wave < 4) {
    // ======================= PRODUCER =======================
    const int p_rel  = wave & 1;       // rel = s*2 + p_rel at step s
    const int p_tile = wave >> 1;      // tile slot 0/1 -> agg rows p_tile*16+
    const int rowb   = p_tile * 16;

    // run bounds for all 8 steps, lane-parallel: lane i = s*2+h
    int ebv = 0;
    {
      int tt = tile0 + p_tile;
      int idx = (tt < N_TILES) ? (tt * 16 + (lane >> 1) * 2 + p_rel + (lane & 1))
                               : N_RUNS;
      if (lane < 16) ebv = run_start[idx];
    }

#define ISSUE16(DST, PV, JB)                                                  \
    _Pragma("unroll")                                                         \
    for (int k1 = 0; k1 < 16; ++k1) {                                         \
      unsigned spq = (unsigned)__builtin_amdgcn_readlane(PV, (JB) + k1);      \
      DST[k1] = xh32[(spq >> 16) * 64 + lane];                                \
    }

#define FLUSHM(BUF)                                                           \
    if (mcur >= 0) {                                                          \
      float sc = __builtin_amdgcn_rcpf((float)scnt);                          \
      *(unsigned*)&agg[BUF][p_rel][rowb + mcur][lane * 2] =                   \
          pack_bf16_2(a0 * sc, a1 * sc);                                      \
    }

#define CONSUME1(SPK, XV, BUF)                                                \
    {                                                                         \
      int mk = (int)((SPK) & 15u);                                            \
      if (mk != mcur) {                                                       \
        FLUSHM(BUF);                                                          \
        mcur = mk; scnt = (int)(((SPK) >> 4) & 4095u);                        \
        a0 = 0.f; a1 = 0.f;                                                   \
      }                                                                       \
      a0 += __uint_as_float((XV) << 16);                                      \
      a1 += __uint_as_float((XV) & 0xffff0000u);                              \
    }

#define CONS16(PV, JB, SLOT, BUF)                                             \
    _Pragma("unroll")                                                         \
    for (int k2 = 0; k2 < 16; ++k2) {                                         \
      unsigned spk = (unsigned)__builtin_amdgcn_readlane(PV, (JB) + k2);      \
      CONSUME1(spk, SLOT[k2], BUF);                                           \
    }

    unsigned xqA[16], xqB[16], xqE[16];

    int e0 = __builtin_amdgcn_readlane(ebv, 0);
    int e1 = __builtin_amdgcn_readlane(ebv, 1);
    int pv = (int)payload[e0 + lane];
    ISSUE16(xqA, pv, 0);

    for (int s = 0; s < 8; ++s) {
      const int buf = s & 1;
      int cnt = e1 - e0;                       // multiple of 16 (padded)

      if (cnt > 16) ISSUE16(xqB, pv, 16);
      if (cnt > 32) ISSUE16(xqE, pv, 32);

      // next step's bounds + payload chunk early
      int f0 = e0, f1 = e1, pvn = pv;
      if (s < 7) {
        f0 = __builtin_amdgcn_readlane(ebv, (s + 1) * 2);
        f1 = __builtin_amdgcn_readlane(ebv, (s + 1) * 2 + 1);
        pvn = (int)payload[f0 + lane];
      }

      // zero my 16 rows (16 x 128 dims): 4 ds_write_b128/lane
      {
        short8 z = {0, 0, 0, 0, 0, 0, 0, 0};
#pragma unroll
        for (int i = 0; i < 4; ++i)
          *(short8*)&agg[buf][p_rel][rowb + i * 4 + q][m16 * 8] = z;
      }

      // consume (all batches full: cnt % 16 == 0)
      {
        int mcur = -1, scnt = 1;
        float a0 = 0.f, a1 = 0.f;
        if (cnt > 0) {
          CONS16(pv, 0, xqA, buf);
          if (cnt > 16) {
            CONS16(pv, 16, xqB, buf);
            if (cnt > 32) {
              CONS16(pv, 32, xqE, buf);
              if (cnt > 48) {                  // ~0.3% of runs
                ISSUE16(xqB, pv, 48);
                CONS16(pv, 48, xqB, buf);
              }
            }
          }
          for (int c0 = e0 + 64; c0 < e1; c0 += 16) {   // vanishingly rare
            int pvx = (int)payload[c0 + lane];
            ISSUE16(xqE, pvx, 0);
            CONS16(pvx, 0, xqE, buf);
          }
          FLUSHM(buf);
        }
      }

      if (s < 7) {                             // across-barrier prefetch b0
        e0 = f0; e1 = f1; pv = pvn;
        ISSUE16(xqA, pv, 0);
      }
      lds_barrier();                           // no vmcnt drain
    }
#undef CONS16
#undef CONSUME1
#undef FLUSHM
#undef ISSUE16
    return;                                    // producers exit; 8 barriers done
  }

  // ======================= CONSUMER =======================
  const int cw = wave - 4;                // owns cols cw*32 .. cw*32+32
  f32x4 acc[2][2];
#pragma unroll
  for (int t = 0; t < 2; ++t)
#pragma unroll
    for (int i = 0; i < 2; ++i) acc[t][i] = (f32x4){0.f, 0.f, 0.f, 0.f};

  for (int s = 0; s < 8; ++s) {
    lds_barrier();                        // barrier s: agg[s&1] ready
#pragma unroll
    for (int rp = 0; rp < 2; ++rp) {
      int rel = s * 2 + rp;
      short8 Bf[4][2];
#pragma unroll
      for (int kk = 0; kk < 4; ++kk)
#pragma unroll
        for (int i = 0; i < 2; ++i)
          Bf[kk][i] = *(const short8*)(Bs +
              ((size_t)((rel * 4 + kk) * 8 + (cw * 2 + i)) << 9) + lane * 8);
#pragma unroll
      for (int kk = 0; kk < 4; ++kk) {
        short8 A0 = *(const short8*)&agg[s & 1][rp][m16][kk * 32 + q * 8];
        short8 A1 = *(const short8*)&agg[s & 1][rp][16 + m16][kk * 32 + q * 8];
#pragma unroll
        for (int i = 0; i < 2; ++i) {
          acc[0][i] = __builtin_amdgcn_mfma_f32_16x16x32_bf16(A0, Bf[kk][i], acc[0][i], 0, 0, 0);
          acc[1][i] = __builtin_amdgcn_mfma_f32_16x16x32_bf16(A1, Bf[kk][i], acc[1][i], 0, 0, 0);
        }
      }
    }
  }

  // ---- root (rel index 16): A from global xh rows of this block ----
  {
    short8 Bf[4][2];
#pragma unroll
    for (int kk = 0; kk < 4; ++kk)
#pragma unroll
      for (int i = 0; i < 2; ++i)
        Bf[kk][i] = *(const short8*)(Bs +
            ((size_t)((16 * 4 + kk) * 8 + (cw * 2 + i)) << 9) + lane * 8);
    int r0 = tile0 * 16 + m16;      if (r0 > N_NODES) r0 = N_NODES;
    int r1 = tile0 * 16 + 16 + m16; if (r1 > N_NODES) r1 = N_NODES;
#pragma unroll
    for (int kk = 0; kk < 4; ++kk) {
      short8 A0 = *(const short8*)(xh + (size_t)r0 * HID + kk * 32 + q * 8);
      short8 A1 = *(const short8*)(xh + (size_t)r1 * HID + kk * 32 + q * 8);
#pragma unroll
      for (int i = 0; i < 2; ++i) {
        acc[0][i] = __builtin_amdgcn_mfma_f32_16x16x32_bf16(A0, Bf[kk][i], acc[0][i], 0, 0, 0);
        acc[1][i] = __builtin_amdgcn_mfma_f32_16x16x32_bf16(A1, Bf[kk][i], acc[1][i], 0, 0, 0);
      }
    }
  }

  // ---- epilogue: bias (+relu+bf16 or f32). C/D: col=lane&15, row=q*4+reg
  float bvv[2];
#pragma unroll
  for (int i = 0; i < 2; ++i) bvv[i] = bias[cw * 32 + i * 16 + m16];
  int rbase = tile0 * 16 + q * 4;
#pragma unroll
  for (int t = 0; t < 2; ++t)
#pragma unroll
    for (int rg = 0; rg < 4; ++rg) {
      int row = rbase + t * 16 + rg;
      if (row < N_NODES) {
#pragma unroll
        for (int i = 0; i < 2; ++i) {
          float v = acc[t][i][rg] + bvv[i];
          int col = cw * 32 + i * 16 + m16;
          if (write_f32) {
            fout[(size_t)row * HID + col] = v;
          } else {
            v = fmaxf(v, 0.f);
            union { __hip_bfloat16 h; ushort_t u; } cv;
            cv.h = __float2bfloat16(v);
            xh_out[(size_t)row * HID + col] = cv.u;
          }
        }
      }
    }
}

// ---------------- host ----------------

extern "C" void kernel_launch(void* const* d_in, const int* in_sizes, int n_in,
                              void* d_out, int out_size, void* d_ws, size_t ws_size,
                              hipStream_t stream) {
  const int*   ei        = (const int*)d_in[0];     // (2, E) int32
  const int*   et        = (const int*)d_in[1];     // (E,)   int32
  const float* node_init = (const float*)d_in[2];   // (N, H) f32
  const float* W         = (const float*)d_in[3];   // (3, 16, H, H) f32
  const float* root      = (const float*)d_in[4];   // (3, H, H) f32
  const float* bias      = (const float*)d_in[5];   // (3, H) f32
  float* outp = (float*)d_out;

  char* ws = (char*)d_ws;
  size_t o = 0;
  auto carve = [&](size_t bytes) { char* p = ws + o; o = (o + bytes + 255) & ~(size_t)255; return p; };
  ushort_t* xh_a       = (ushort_t*)carve((size_t)(N_NODES + 1) * HID * 2);   // +dummy row
  ushort_t* xh_b       = (ushort_t*)carve((size_t)(N_NODES + 1) * HID * 2);
  unsigned* payload    = (unsigned*)carve((size_t)PAYLOAD_CAP * 4);
  int*      cnt        = (int*)     carve((size_t)N_BINS * 4);
  int*      fine_start = (int*)     carve((size_t)N_BINS * 4);
  int*      rank       = (int*)     carve((size_t)N_EDGES * 4);
  int*      run_start  = (int*)     carve((size_t)(N_RUNS + 1) * 4);
  int*      totals     = (int*)     carve((size_t)N_SCANBLK * 4);
  ushort_t* Bs         = (ushort_t*)carve((size_t)3 * BS_LAYER * 2);
  (void)ws_size; (void)n_in; (void)in_sizes; (void)out_size;

  // ---- setup: padded counting sort by (tile, rel, m) + B swizzle ----
  hipMemsetAsync(cnt, 0, (size_t)N_BINS * 4, stream);
  hipLaunchKernelGGL(k_hist,         dim3(N_EDGES / 256), dim3(256), 0, stream, ei, et, cnt, rank);
  hipLaunchKernelGGL(k_runpad_btot,  dim3(N_SCANBLK), dim3(1024), 0, stream, cnt, run_start, totals);
  hipLaunchKernelGGL(k_scan_totals,  dim3(1), dim3(1024), 0, stream, totals, run_start + N_RUNS, N_SCANBLK);
  hipLaunchKernelGGL(k_scan_fineoff, dim3(N_SCANBLK), dim3(1024), 0, stream, run_start, totals, cnt, fine_start, payload);
  hipLaunchKernelGGL(k_sort,         dim3(N_EDGES / 256), dim3(256), 0, stream, ei, et, cnt, fine_start, rank, payload);
  hipLaunchKernelGGL(k_bt,           dim3(3 * 544 * 64 / 256), dim3(256), 0, stream, W, root, Bs);
  hipLaunchKernelGGL(k_xh,           dim3(N_NODES * HID / 4 / 256), dim3(256), 0, stream, node_init, xh_a, xh_b);

  // ---- 3 layers, bf16 ping-pong; relu fused into epilogue of layers 0,1 ----
  hipLaunchKernelGGL(k_main, dim3(N_MBLK), dim3(512), 0, stream,
                     xh_a, xh_b, (float*)nullptr,
                     Bs + (size_t)0 * BS_LAYER, bias + 0 * HID, run_start, payload, 0);
  hipLaunchKernelGGL(k_main, dim3(N_MBLK), dim3(512), 0, stream,
                     xh_b, xh_a, (float*)nullptr,
                     Bs + (size_t)1 * BS_LAYER, bias + 1 * HID, run_start, payload, 0);
  hipLaunchKernelGGL(k_main, dim3(N_MBLK), dim3(512), 0, stream,
                     xh_a, (ushort_t*)nullptr, outp,
                     Bs + (size_t)2 * BS_LAYER, bias + 2 * HID, run_start, payload, 1);
}

// Round 10
// 496.068 us; speedup vs baseline: 1.2336x; 1.0261x over previous
//
#include <hip/hip_runtime.h>
#include <hip/hip_bf16.h>

#define N_NODES   50000
#define N_REL     16
#define HID       128
#define N_EDGES   1600000
#define N_TILES   3125          // N_NODES/16
#define N_BINS    800000        // fine bins (tile, rel, m)
#define N_RUNS    50000         // (tile, rel) runs of 16 fine bins
#define N_SCANBLK 49            // ceil(N_RUNS/1024)
#define N_MBLK    1563          // ceil(3125/2): M=32 per block
#define PAYLOAD_CAP 2400064     // E + 50000*15 pad worst case + slack
#define BS_LAYER  278528        // (16 rel + root)*4kk*8cb frags * 512 ushorts
#define AG_STRIDE 136           // ushorts per agg row (272 B, 16-B aligned)
#define XH_BLKS   6250          // N_NODES*HID/4/256
#define BT_BLKS   408           // 3*544*64/256

typedef unsigned short ushort_t;
typedef __attribute__((ext_vector_type(8))) short short8;
typedef __attribute__((ext_vector_type(4))) float f32x4;

union BF2U { __hip_bfloat162 h; unsigned u; };

__device__ __forceinline__ unsigned pack_bf16_2(float x, float y) {
  BF2U c; c.h = __float22bfloat162_rn(make_float2(x, y));
  return c.u;
}

// barrier WITHOUT vmcnt drain (LDS ops drained; global prefetches keep flying)
__device__ __forceinline__ void lds_barrier() {
  asm volatile("s_waitcnt lgkmcnt(0)\n\ts_barrier" ::: "memory");
}

// ---------------- setup kernels ----------------

// counts per fine bin + packed key/rank per edge (key<2^20, rank<2^12)
__global__ __launch_bounds__(256) void k_hist(const int* __restrict__ ei,
                                              const int* __restrict__ et,
                                              int* __restrict__ cnt,
                                              unsigned* __restrict__ keyrank) {
  int e = blockIdx.x * 256 + threadIdx.x;   // grid covers E exactly
  int tgt = ei[N_EDGES + e];
  int r   = et[e];
  int key = ((tgt >> 4) << 8) | (r << 4) | (tgt & 15);
  int rk  = atomicAdd(&cnt[key], 1);
  keyrank[e] = ((unsigned)key << 12) | (unsigned)rk;
}

// ONE kernel: per-run padded totals -> block scan -> atomic block base
// (dispatch-order-independent) -> run2 {start,padcnt} + fine-bin starts +
// dummy fill. Replaces the old 3-launch scan chain; payload layout varies
// run-to-run (atomic order) but results are identical.
__global__ __launch_bounds__(1024) void k_scanall(const int* __restrict__ cnt,
                                                  int* __restrict__ run2,
                                                  int* __restrict__ fine_start,
                                                  unsigned* __restrict__ payload,
                                                  int* __restrict__ cursor) {
  __shared__ int s[1024];
  __shared__ int basesh;
  int t = threadIdx.x, blk = blockIdx.x;
  int r = blk * 1024 + t;
  int4 c4[4];
  int v = 0;
  if (r < N_RUNS) {
    const int4* cp = (const int4*)(cnt + r * 16);
    int sum = 0;
#pragma unroll
    for (int j = 0; j < 4; ++j) { c4[j] = cp[j]; sum += c4[j].x + c4[j].y + c4[j].z + c4[j].w; }
    v = (sum + 15) & ~15;
  }
  s[t] = v; __syncthreads();
  for (int ofs = 1; ofs < 1024; ofs <<= 1) {
    int x = (t >= ofs) ? s[t - ofs] : 0;
    __syncthreads();
    s[t] += x;
    __syncthreads();
  }
  if (t == 1023) basesh = atomicAdd(cursor, s[1023]);
  __syncthreads();
  if (r < N_RUNS) {
    int base = basesh + s[t] - v;           // exclusive offset of my run
    run2[r * 2]     = base;
    run2[r * 2 + 1] = v;                    // padded count
    int c16[16];
    c16[0]=c4[0].x; c16[1]=c4[0].y; c16[2]=c4[0].z; c16[3]=c4[0].w;
    c16[4]=c4[1].x; c16[5]=c4[1].y; c16[6]=c4[1].z; c16[7]=c4[1].w;
    c16[8]=c4[2].x; c16[9]=c4[2].y; c16[10]=c4[2].z; c16[11]=c4[2].w;
    c16[12]=c4[3].x; c16[13]=c4[3].y; c16[14]=c4[3].z; c16[15]=c4[3].w;
    int pfx = 0;
#pragma unroll
    for (int i = 0; i < 16; ++i) {
      fine_start[r * 16 + i] = base + pfx;
      pfx += c16[i];
    }
    const unsigned dummy = ((unsigned)N_NODES << 16) | (1u << 4) | 15u;
    for (int j = base + pfx; j < base + v; ++j) payload[j] = dummy;
  }
}

// payload = src:31..16 | bin_cnt:15..4 | m:3..0 — atomic-free placement;
// reads only src + packed keyrank (et/tgt not re-read)
__global__ __launch_bounds__(256) void k_sort(const int* __restrict__ ei,
                                              const int* __restrict__ cnt,
                                              const int* __restrict__ fine_start,
                                              const unsigned* __restrict__ keyrank,
                                              unsigned* __restrict__ payload) {
  int e = blockIdx.x * 256 + threadIdx.x;
  int src = ei[e];
  unsigned kr = keyrank[e];
  int key = (int)(kr >> 12);
  int rk  = (int)(kr & 4095u);
  int c = cnt[key]; c = c > 4095 ? 4095 : c;
  int pos = fine_start[key] + rk;
  payload[pos] = ((unsigned)src << 16) | ((unsigned)c << 4) | (unsigned)(key & 15);
}

// FUSED Bs swizzle + xh convert + dummy-row zero (blockIdx split).
// Bs fragment-ordered: frag = ((r*4+kk)*8+cb), r 0..16 (16=root); within frag
// 64 lanes x 8 bf16: lane -> col cb*16+(lane&15), k = kk*32+(lane>>4)*8+j.
__global__ __launch_bounds__(256) void k_btxh(const float* __restrict__ W,
                                              const float* __restrict__ root,
                                              ushort_t* __restrict__ Bs,
                                              const float* __restrict__ xin,
                                              ushort_t* __restrict__ xh_a,
                                              ushort_t* __restrict__ xh_b) {
  if (blockIdx.x < XH_BLKS) {
    int i = blockIdx.x * 256 + threadIdx.x;    // N*H/4 exact
    float4 v = ((const float4*)xin)[i];
    uint2 u;
    u.x = pack_bf16_2(v.x, v.y);
    u.y = pack_bf16_2(v.z, v.w);
    ((uint2*)xh_a)[i] = u;
    if (blockIdx.x == 0 && threadIdx.x < 64) {
      uint2 z = {0u, 0u};
      ushort_t* dst = (threadIdx.x < 32) ? xh_a : xh_b;
      int k = threadIdx.x & 31;
      *(uint2*)(dst + (size_t)N_NODES * HID + k * 4) = z;
    }
    return;
  }
  int idx = (blockIdx.x - XH_BLKS) * 256 + threadIdx.x;   // 3*544*64 exact
  int lane = idx & 63;
  int fl   = idx >> 6;                          // l*544 + frag
  int frag = fl % 544;
  int l    = fl / 544;
  int cb = frag & 7, kk = (frag >> 3) & 3, r = frag >> 5;
  int col = cb * 16 + (lane & 15);
  int d0  = kk * 32 + (lane >> 4) * 8;
  const float* srcp = (r < 16)
      ? W + ((size_t)(l * N_REL + r) * HID + d0) * HID + col
      : root + ((size_t)l * HID + d0) * HID + col;
  ushort_t out[8];
#pragma unroll
  for (int j = 0; j < 8; ++j) {
    union { __hip_bfloat16 h; ushort_t u; } c;
    c.h = __float2bfloat16(srcp[(size_t)j * HID]);
    out[j] = c.u;
  }
  *(short8*)(Bs + ((size_t)fl << 9) + lane * 8) = *(short8*)out;
}

// ---------------- fused per-layer kernel: 4 producer + 4 consumer waves ----
// Block = 512 threads = 8 waves, 32 nodes (2 tiles). MLP comes from wave
// count (16 producer waves/CU); run info is {start, padded-cnt} pairs in
// run2 (atomic block bases in k_scanall make run_start[r+1] adjacency
// invalid across scan-block boundaries). Runs padded to x16 -> full batches.

__global__ __launch_bounds__(512, 8) void k_main(const ushort_t* __restrict__ xh,
                                                 ushort_t* __restrict__ xh_out,
                                                 float* __restrict__ fout,
                                                 const ushort_t* __restrict__ Bs,
                                                 const float* __restrict__ bias,
                                                 const int* __restrict__ run2,
                                                 const unsigned* __restrict__ payload,
                                                 int write_f32) {
  __shared__ alignas(16) ushort_t agg[2][2][32][AG_STRIDE];   // 34.8 KB

  const int tile0 = blockIdx.x * 2;
  const int tid   = threadIdx.x;
  const int wave  = tid >> 6;
  const int lane  = tid & 63;
  const int m16   = lane & 15;
  const int q     = lane >> 4;
  const unsigned* xh32 = (const unsigned*)xh;

  if (wave < 4) {
    // ======================= PRODUCER =======================
    const int p_rel  = wave & 1;       // rel = s*2 + p_rel at step s
    const int p_tile = wave >> 1;      // tile slot 0/1 -> agg rows p_tile*16+
    const int rowb   = p_tile * 16;

    // run info for all 8 steps, lane-parallel: lane = s*2+h
    // h=0 -> start, h=1 -> padded count
    int ebv = 0;
    {
      int tt = tile0 + p_tile;
      if (lane < 16 && tt < N_TILES) {
        int rid = tt * 16 + ((lane >> 1) << 1) + p_rel;   // run for step lane>>1
        ebv = run2[rid * 2 + (lane & 1)];
      }
    }

#define ISSUE16(DST, PV, JB)                                                  \
    _Pragma("unroll")                                                         \
    for (int k1 = 0; k1 < 16; ++k1) {                                         \
      unsigned spq = (unsigned)__builtin_amdgcn_readlane(PV, (JB) + k1);      \
      DST[k1] = xh32[(spq >> 16) * 64 + lane];                                \
    }

#define FLUSHM(BUF)                                                           \
    if (mcur >= 0) {                                                          \
      float sc = __builtin_amdgcn_rcpf((float)scnt);                          \
      *(unsigned*)&agg[BUF][p_rel][rowb + mcur][lane * 2] =                   \
          pack_bf16_2(a0 * sc, a1 * sc);                                      \
    }

#define CONSUME1(SPK, XV, BUF)                                                \
    {                                                                         \
      int mk = (int)((SPK) & 15u);                                            \
      if (mk != mcur) {                                                       \
        FLUSHM(BUF);                                                          \
        mcur = mk; scnt = (int)(((SPK) >> 4) & 4095u);                        \
        a0 = 0.f; a1 = 0.f;                                                   \
      }                                                                       \
      a0 += __uint_as_float((XV) << 16);                                      \
      a1 += __uint_as_float((XV) & 0xffff0000u);                              \
    }

#define CONS16(PV, JB, SLOT, BUF)                                             \
    _Pragma("unroll")                                                         \
    for (int k2 = 0; k2 < 16; ++k2) {                                         \
      unsigned spk = (unsigned)__builtin_amdgcn_readlane(PV, (JB) + k2);      \
      CONSUME1(spk, SLOT[k2], BUF);                                           \
    }

    unsigned xqA[16], xqB[16], xqE[16];

    int e0   = __builtin_amdgcn_readlane(ebv, 0);
    int rcnt = __builtin_amdgcn_readlane(ebv, 1);
    int pv = (int)payload[e0 + lane];
    ISSUE16(xqA, pv, 0);

    for (int s = 0; s < 8; ++s) {
      const int buf = s & 1;
      int cnt = rcnt;                          // multiple of 16 (padded)

      if (cnt > 16) ISSUE16(xqB, pv, 16);
      if (cnt > 32) ISSUE16(xqE, pv, 32);

      // next step's bounds + payload chunk early
      int f0 = e0, fcnt = rcnt, pvn = pv;
      if (s < 7) {
        f0   = __builtin_amdgcn_readlane(ebv, (s + 1) * 2);
        fcnt = __builtin_amdgcn_readlane(ebv, (s + 1) * 2 + 1);
        pvn = (int)payload[f0 + lane];
      }

      // zero my 16 rows (16 x 128 dims): 4 ds_write_b128/lane
      {
        short8 z = {0, 0, 0, 0, 0, 0, 0, 0};
#pragma unroll
        for (int i = 0; i < 4; ++i)
          *(short8*)&agg[buf][p_rel][rowb + i * 4 + q][m16 * 8] = z;
      }

      // consume (all batches full: cnt % 16 == 0)
      {
        int mcur = -1, scnt = 1;
        float a0 = 0.f, a1 = 0.f;
        if (cnt > 0) {
          CONS16(pv, 0, xqA, buf);
          if (cnt > 16) {
            CONS16(pv, 16, xqB, buf);
            if (cnt > 32) {
              CONS16(pv, 32, xqE, buf);
              if (cnt > 48) {                  // ~4% of runs
                ISSUE16(xqB, pv, 48);
                CONS16(pv, 48, xqB, buf);
              }
            }
          }
          for (int c0 = e0 + 64; c0 < e0 + cnt; c0 += 16) {  // vanishingly rare
            int pvx = (int)payload[c0 + lane];
            ISSUE16(xqE, pvx, 0);
            CONS16(pvx, 0, xqE, buf);
          }
          FLUSHM(buf);
        }
      }

      if (s < 7) {                             // across-barrier prefetch b0
        e0 = f0; rcnt = fcnt; pv = pvn;
        ISSUE16(xqA, pv, 0);
      }
      lds_barrier();                           // no vmcnt drain
    }
#undef CONS16
#undef CONSUME1
#undef FLUSHM
#undef ISSUE16
    return;                                    // producers exit; 8 barriers done
  }

  // ======================= CONSUMER =======================
  const int cw = wave - 4;                // owns cols cw*32 .. cw*32+32
  f32x4 acc[2][2];
#pragma unroll
  for (int t = 0; t < 2; ++t)
#pragma unroll
    for (int i = 0; i < 2; ++i) acc[t][i] = (f32x4){0.f, 0.f, 0.f, 0.f};

  for (int s = 0; s < 8; ++s) {
    lds_barrier();                        // barrier s: agg[s&1] ready
#pragma unroll
    for (int rp = 0; rp < 2; ++rp) {
      int rel = s * 2 + rp;
      short8 Bf[4][2];
#pragma unroll
      for (int kk = 0; kk < 4; ++kk)
#pragma unroll
        for (int i = 0; i < 2; ++i)
          Bf[kk][i] = *(const short8*)(Bs +
              ((size_t)((rel * 4 + kk) * 8 + (cw * 2 + i)) << 9) + lane * 8);
#pragma unroll
      for (int kk = 0; kk < 4; ++kk) {
        short8 A0 = *(const short8*)&agg[s & 1][rp][m16][kk * 32 + q * 8];
        short8 A1 = *(const short8*)&agg[s & 1][rp][16 + m16][kk * 32 + q * 8];
#pragma unroll
        for (int i = 0; i < 2; ++i) {
          acc[0][i] = __builtin_amdgcn_mfma_f32_16x16x32_bf16(A0, Bf[kk][i], acc[0][i], 0, 0, 0);
          acc[1][i] = __builtin_amdgcn_mfma_f32_16x16x32_bf16(A1, Bf[kk][i], acc[1][i], 0, 0, 0);
        }
      }
    }
  }

  // ---- root (rel index 16): A from global xh rows of this block ----
  {
    short8 Bf[4][2];
#pragma unroll
    for (int kk = 0; kk < 4; ++kk)
#pragma unroll
      for (int i = 0; i < 2; ++i)
        Bf[kk][i] = *(const short8*)(Bs +
            ((size_t)((16 * 4 + kk) * 8 + (cw * 2 + i)) << 9) + lane * 8);
    int r0 = tile0 * 16 + m16;      if (r0 > N_NODES) r0 = N_NODES;
    int r1 = tile0 * 16 + 16 + m16; if (r1 > N_NODES) r1 = N_NODES;
#pragma unroll
    for (int kk = 0; kk < 4; ++kk) {
      short8 A0 = *(const short8*)(xh + (size_t)r0 * HID + kk * 32 + q * 8);
      short8 A1 = *(const short8*)(xh + (size_t)r1 * HID + kk * 32 + q * 8);
#pragma unroll
      for (int i = 0; i < 2; ++i) {
        acc[0][i] = __builtin_amdgcn_mfma_f32_16x16x32_bf16(A0, Bf[kk][i], acc[0][i], 0, 0, 0);
        acc[1][i] = __builtin_amdgcn_mfma_f32_16x16x32_bf16(A1, Bf[kk][i], acc[1][i], 0, 0, 0);
      }
    }
  }

  // ---- epilogue: bias (+relu+bf16 or f32). C/D: col=lane&15, row=q*4+reg
  float bvv[2];
#pragma unroll
  for (int i = 0; i < 2; ++i) bvv[i] = bias[cw * 32 + i * 16 + m16];
  int rbase = tile0 * 16 + q * 4;
#pragma unroll
  for (int t = 0; t < 2; ++t)
#pragma unroll
    for (int rg = 0; rg < 4; ++rg) {
      int row = rbase + t * 16 + rg;
      if (row < N_NODES) {
#pragma unroll
        for (int i = 0; i < 2; ++i) {
          float v = acc[t][i][rg] + bvv[i];
          int col = cw * 32 + i * 16 + m16;
          if (write_f32) {
            fout[(size_t)row * HID + col] = v;
          } else {
            v = fmaxf(v, 0.f);
            union { __hip_bfloat16 h; ushort_t u; } cv;
            cv.h = __float2bfloat16(v);
            xh_out[(size_t)row * HID + col] = cv.u;
          }
        }
      }
    }
}

// ---------------- host ----------------

extern "C" void kernel_launch(void* const* d_in, const int* in_sizes, int n_in,
                              void* d_out, int out_size, void* d_ws, size_t ws_size,
                              hipStream_t stream) {
  const int*   ei        = (const int*)d_in[0];     // (2, E) int32
  const int*   et        = (const int*)d_in[1];     // (E,)   int32
  const float* node_init = (const float*)d_in[2];   // (N, H) f32
  const float* W         = (const float*)d_in[3];   // (3, 16, H, H) f32
  const float* root      = (const float*)d_in[4];   // (3, H, H) f32
  const float* bias      = (const float*)d_in[5];   // (3, H) f32
  float* outp = (float*)d_out;

  char* ws = (char*)d_ws;
  size_t o = 0;
  auto carve = [&](size_t bytes) { char* p = ws + o; o = (o + bytes + 255) & ~(size_t)255; return p; };
  ushort_t* xh_a       = (ushort_t*)carve((size_t)(N_NODES + 1) * HID * 2);   // +dummy row
  ushort_t* xh_b       = (ushort_t*)carve((size_t)(N_NODES + 1) * HID * 2);
  unsigned* payload    = (unsigned*)carve((size_t)PAYLOAD_CAP * 4);
  int*      cnt        = (int*)     carve((size_t)(N_BINS + 64) * 4);  // +cursor word
  int*      fine_start = (int*)     carve((size_t)N_BINS * 4);
  unsigned* keyrank    = (unsigned*)carve((size_t)N_EDGES * 4);
  int*      run2       = (int*)     carve((size_t)(N_RUNS * 2 + 2) * 4);
  ushort_t* Bs         = (ushort_t*)carve((size_t)3 * BS_LAYER * 2);
  int*      cursor     = cnt + N_BINS;
  (void)ws_size; (void)n_in; (void)in_sizes; (void)out_size;

  // ---- setup: padded counting sort by (tile, rel, m) + B swizzle + xh ----
  hipMemsetAsync(cnt, 0, (size_t)(N_BINS + 64) * 4, stream);
  hipLaunchKernelGGL(k_hist,    dim3(N_EDGES / 256), dim3(256), 0, stream, ei, et, cnt, keyrank);
  hipLaunchKernelGGL(k_scanall, dim3(N_SCANBLK), dim3(1024), 0, stream, cnt, run2, fine_start, payload, cursor);
  hipLaunchKernelGGL(k_sort,    dim3(N_EDGES / 256), dim3(256), 0, stream, ei, cnt, fine_start, keyrank, payload);
  hipLaunchKernelGGL(k_btxh,    dim3(XH_BLKS + BT_BLKS), dim3(256), 0, stream, W, root, Bs, node_init, xh_a, xh_b);

  // ---- 3 layers, bf16 ping-pong; relu fused into epilogue of layers 0,1 ----
  hipLaunchKernelGGL(k_main, dim3(N_MBLK), dim3(512), 0, stream,
                     xh_a, xh_b, (float*)nullptr,
                     Bs + (size_t)0 * BS_LAYER, bias + 0 * HID, run2, payload, 0);
  hipLaunchKernelGGL(k_main, dim3(N_MBLK), dim3(512), 0, stream,
                     xh_b, xh_a, (float*)nullptr,
                     Bs + (size_t)1 * BS_LAYER, bias + 1 * HID, run2, payload, 0);
  hipLaunchKernelGGL(k_main, dim3(N_MBLK), dim3(512), 0, stream,
                     xh_a, (ushort_t*)nullptr, outp,
                     Bs + (size_t)2 * BS_LAYER, bias + 2 * HID, run2, payload, 1);
}